// Round 13
// baseline (155.360 us; speedup 1.0000x reference)
//
#include <hip/hip_runtime.h>
#include <math.h>

#define ALPHA 32.0f
#define MRG 0.1f
#define STAT_WEIGHT 0.01f
#define STAT_ADJ_W 0.15f
#define COS_EPS 1e-8f

typedef __attribute__((ext_vector_type(8))) short bf16x8;
typedef __attribute__((ext_vector_type(4))) float f32x4;
typedef __attribute__((ext_vector_type(4))) unsigned int u32x4;

__device__ __forceinline__ ushort f2bf(float f) {
    unsigned u = __float_as_uint(f);
    return (ushort)((u + 0x7FFFu + ((u >> 16) & 1u)) >> 16);   // RNE
}
__device__ __forceinline__ unsigned pk2(float a, float b) {
    return (unsigned)f2bf(a) | ((unsigned)f2bf(b) << 16);
}

// 128-active-lane block reduce (tid<128 contribute; all 256 threads barrier).
// Values bit-identical to the original 128-thread bred128.
__device__ __forceinline__ float bredL(float v, float* sm, int tid) {
    #pragma unroll
    for (int off = 1; off < 64; off <<= 1) v += __shfl_xor(v, off);
    if ((tid & 63) == 0 && tid < 128) sm[tid >> 6] = v;
    __syncthreads();
    float r = sm[0] + sm[1];
    __syncthreads();
    return r;
}

// ---------------- K1: GEMM, self-normalizing (R11 phases 0+1, proven) --------
// 512 blocks, (256,2) mapping. Phase 0: normalize own 256 rows directly from X
// into swizzled LDS (reduction replicates the shuffle-tree order exactly ->
// bit-identical xn; verified absmax 0.0 in R11). Phase 1: barrier-free slice
// loop, desymmetrized start, single-writer plain stores into PA/PB.
// Needs NOTHING from other kernels; zeroes scal[8] for k_sf.
__launch_bounds__(256, 2)
__global__ void k_main(const float* __restrict__ X, const float* __restrict__ proxies,
                       const int* __restrict__ T, float* __restrict__ PN,
                       float* __restrict__ scal, int C, int nslice) {
    const int tid = threadIdx.x, lane = tid & 63, wv = tid >> 6;
    const int nlo = lane & 15, quad = lane >> 4;
    const int bid = blockIdx.x;
    const int x = bid & 255, half = bid >> 8;     // (256,2) GEMM mapping

    __shared__ ushort Sx[32768];                  // 64 KB: 256 rows x 256 B
    __shared__ alignas(16) int Tg[256];

    if (bid == 0 && tid < 8) scal[tid] = 0.f;     // consumed by k_sf (next disp)

    // ---- Phase 0: normalize own 256 rows into swizzled LDS ----
    {
        const int row = tid;
        const float4* xr = (const float4*)(X + (size_t)(half * 256 + row) * 128);
        float s32[32];
        #pragma unroll
        for (int g = 0; g < 32; ++g) {
            float4 v = xr[g];
            s32[g] = (v.x * v.x + v.y * v.y) + (v.z * v.z + v.w * v.w);
        }
        #pragma unroll
        for (int w = 16; w >= 1; w >>= 1)
            #pragma unroll
            for (int g = 0; g < w; ++g) s32[g] = s32[2 * g] + s32[2 * g + 1];
        float pin = rsqrtf(s32[0] + 1e-12f);
        uint4* dst = (uint4*)Sx + row * 16;       // 16 x 16B groups per row
        #pragma unroll
        for (int g = 0; g < 16; ++g) {
            float4 a = xr[g * 2], b4 = xr[g * 2 + 1];
            u32x4 u;
            u.x = pk2(a.x * pin, a.y * pin);
            u.y = pk2(a.z * pin, a.w * pin);
            u.z = pk2(b4.x * pin, b4.y * pin);
            u.w = pk2(b4.z * pin, b4.w * pin);
            dst[g ^ (row & 15)] = __builtin_bit_cast(uint4, u);
        }
    }
    Tg[tid] = T[half * 256 + tid];
    __syncthreads();                              // rows staged (only barrier)

    // ---- Phase 1: GEMM (R10-proven body) ----
    float* PA = PN + (size_t)half * 2 * C;        // half0 -> A, half1 -> B
    float* NA = PA + C;

    int fro[4];
    #pragma unroll
    for (int ks = 0; ks < 4; ++ks)
        fro[ks] = nlo * 128 + (((ks * 4 + quad) ^ nlo) << 3);

    const int s0 = (x + (half ? 128 : 0)) & 255;  // desymmetrized start
    for (int s = s0; s < nslice; s += 256) {
        const int c0 = s * 128;
        const int cls0 = c0 + wv * 32 + nlo;
        const int cls1 = cls0 + 16;

        bf16x8 bfr[2][4];
        #pragma unroll
        for (int t = 0; t < 2; ++t) {
            int cls = c0 + wv * 32 + t * 16 + nlo;
            int cl = (cls < C) ? cls : C - 1;
            const float4* pr = (const float4*)(proxies + (size_t)cl * 128);
            float4 v0[4], v1[4];
            float s2 = 0.f;
            #pragma unroll
            for (int ks = 0; ks < 4; ++ks) {
                v0[ks] = pr[ks * 8 + quad * 2];
                v1[ks] = pr[ks * 8 + quad * 2 + 1];
                s2 += v0[ks].x*v0[ks].x + v0[ks].y*v0[ks].y + v0[ks].z*v0[ks].z + v0[ks].w*v0[ks].w
                    + v1[ks].x*v1[ks].x + v1[ks].y*v1[ks].y + v1[ks].z*v1[ks].z + v1[ks].w*v1[ks].w;
            }
            s2 += __shfl_xor(s2, 16);
            s2 += __shfl_xor(s2, 32);
            float pin = rsqrtf(s2 + 1e-12f);
            #pragma unroll
            for (int ks = 0; ks < 4; ++ks) {
                u32x4 u;
                u.x = pk2(v0[ks].x * pin, v0[ks].y * pin);
                u.y = pk2(v0[ks].z * pin, v0[ks].w * pin);
                u.z = pk2(v1[ks].x * pin, v1[ks].y * pin);
                u.w = pk2(v1[ks].z * pin, v1[ks].w * pin);
                bfr[t][ks] = __builtin_bit_cast(bf16x8, u);
            }
        }

        float pp0 = 0.f, np0 = 0.f, pp1 = 0.f, np1 = 0.f;
        #pragma unroll 4
        for (int rt = 0; rt < 16; ++rt) {
            const ushort* sb = &Sx[rt * 2048];
            bf16x8 a0 = *(const bf16x8*)&sb[fro[0]];
            bf16x8 a1 = *(const bf16x8*)&sb[fro[1]];
            bf16x8 a2 = *(const bf16x8*)&sb[fro[2]];
            bf16x8 a3 = *(const bf16x8*)&sb[fro[3]];
            f32x4 acc0 = {0.f,0.f,0.f,0.f}, acc1 = {0.f,0.f,0.f,0.f};
            acc0 = __builtin_amdgcn_mfma_f32_16x16x32_bf16(a0, bfr[0][0], acc0, 0, 0, 0);
            acc1 = __builtin_amdgcn_mfma_f32_16x16x32_bf16(a0, bfr[1][0], acc1, 0, 0, 0);
            acc0 = __builtin_amdgcn_mfma_f32_16x16x32_bf16(a1, bfr[0][1], acc0, 0, 0, 0);
            acc1 = __builtin_amdgcn_mfma_f32_16x16x32_bf16(a1, bfr[1][1], acc1, 0, 0, 0);
            acc0 = __builtin_amdgcn_mfma_f32_16x16x32_bf16(a2, bfr[0][2], acc0, 0, 0, 0);
            acc1 = __builtin_amdgcn_mfma_f32_16x16x32_bf16(a2, bfr[1][2], acc1, 0, 0, 0);
            acc0 = __builtin_amdgcn_mfma_f32_16x16x32_bf16(a3, bfr[0][3], acc0, 0, 0, 0);
            acc1 = __builtin_amdgcn_mfma_f32_16x16x32_bf16(a3, bfr[1][3], acc1, 0, 0, 0);

            int4 t4 = *(const int4*)&Tg[rt * 16 + quad * 4];
            int tvs[4] = {t4.x, t4.y, t4.z, t4.w};
            #pragma unroll
            for (int r = 0; r < 4; ++r) {
                { bool po = (tvs[r] == cls0); float v = acc0[r];
                  float e = __expf(po ? -ALPHA * (v - MRG) : ALPHA * (v + MRG));
                  pp0 += po ? e : 0.f; np0 += po ? 0.f : e; }
                { bool po = (tvs[r] == cls1); float v = acc1[r];
                  float e = __expf(po ? -ALPHA * (v - MRG) : ALPHA * (v + MRG));
                  pp1 += po ? e : 0.f; np1 += po ? 0.f : e; }
            }
        }

        pp0 += __shfl_xor(pp0, 16); pp0 += __shfl_xor(pp0, 32);
        np0 += __shfl_xor(np0, 16); np0 += __shfl_xor(np0, 32);
        pp1 += __shfl_xor(pp1, 16); pp1 += __shfl_xor(pp1, 32);
        np1 += __shfl_xor(np1, 16); np1 += __shfl_xor(np1, 32);
        if (quad == 0) {
            if (cls0 < C) { PA[cls0] = pp0; NA[cls0] = np0; }
            if (cls1 < C) { PA[cls1] = pp1; NA[cls1] = np1; }
        }
    }
}

// ---------------- K2: stats + finish, small-LDS high-occupancy ---------------
// 512 blocks x 256 threads, ~4.7 KB LDS -> cc-scan runs at full TLP (the R11
// lesson: never put the BW-phase in a big-LDS kernel). PN complete via stream
// order. Finish partitioned BY CLASS OWNERSHIP (no cross-block handshake):
//   owner block of class c (min sample index): computes adj in registers and
//     the lp/ln/nv terms for c  (p = PA[c]+PB[c] > 0 strictly for owned);
//   unowned classes (p == 0 exactly): grid-stride loop adds log1p(n) only
//     (identical to old a=0 path: __expf(0) == 1).
// Finisher = byte-for-byte the proven k_fin pattern (single tid==0 thread:
// counter bump + conditional assembly; ran correctly R4/R7/R8/R10).
__global__ void k_sf(const float* __restrict__ X, const float* __restrict__ proxies,
                     const float* __restrict__ cc, const int* __restrict__ T,
                     const float* __restrict__ PN, float* __restrict__ scal,
                     float* __restrict__ out, int C, int B, int nblk) {
    const int tid = threadIdx.x, b = blockIdx.x;
    const int lane = tid & 63, wv = tid >> 6;
    const int d = tid & 127;
    const bool lo = tid < 128;
    __shared__ int Tl[512];
    __shared__ int mlist[512];
    __shared__ float sm[2];
    __shared__ float smc[4];
    __shared__ float red[4][3];
    __shared__ int mcnt;

    Tl[tid] = T[tid]; Tl[tid + 256] = T[tid + 256];
    if (tid == 0) mcnt = 0;

    // cc |.| grid-strided partial at full TLP -> atomicAdd into scal[2]
    float cabs = 0.f;
    {
        const float4* cp = (const float4*)cc;
        const int n4 = C * 32;
        #pragma unroll 4
        for (int i = b * 256 + tid; i < n4; i += nblk * 256) {
            float4 v = cp[i];
            cabs += fabsf(v.x) + fabsf(v.y) + fabsf(v.z) + fabsf(v.w);
        }
    }
    #pragma unroll
    for (int off = 1; off < 64; off <<= 1) cabs += __shfl_xor(cabs, off);
    if (lane == 0) smc[wv] = cabs;
    __syncthreads();                              // also covers Tl/mcnt init
    if (tid == 0) atomicAdd(&scal[2], (smc[0] + smc[1]) + (smc[2] + smc[3]));

    const int c = Tl[b];

    // parallel membership scan (mlist order irrelevant: min + rank-sort)
    for (int j = tid; j < B; j += 256)
        if (Tl[j] == c) mlist[atomicAdd(&mcnt, 1)] = j;
    __syncthreads();
    const int cnt = mcnt;
    int minj = mlist[0];
    for (int i = 1; i < cnt; ++i) minj = min(minj, mlist[i]);

    float lp = 0.f, ln = 0.f, nv = 0.f;

    if (minj == b) {                              // owner block (block-uniform)
        // member stats in ascending-j order (bit-identical to serial original)
        float sd = 0.f, qd = 0.f;
        int prev = -1;
        for (int rank = 0; rank < cnt; ++rank) {
            int cur = 0x7fffffff;
            for (int i = 0; i < cnt; ++i) { int v = mlist[i]; if (v > prev && v < cur) cur = v; }
            prev = cur;
            float xj = lo ? X[(size_t)cur * 128 + d] : 0.f;
            float nj = bredL(xj * xj, sm, tid);
            float xnj = xj * rsqrtf(nj + 1e-12f);
            sd += xnj; qd += xnj * xnj;
        }
        float fc = (float)cnt;
        float m = sd / fc;
        float var = fminf(fmaxf(qd / fc - m * m, 1e-6f), 10.0f);
        float sv = bredL(var, sm, tid);

        float p  = lo ? proxies[(size_t)c * 128 + d] : 0.f;
        float cv = lo ? cc[(size_t)c * 128 + d] : 0.f;
        float s2 = bredL(p * p, sm, tid);
        float c2 = bredL(cv * cv, sm, tid);
        float pc = bredL(p * cv, sm, tid);
        if (tid == 0) {
            float inv = rsqrtf(s2 + 1e-12f);
            float pn = fmaxf(sqrtf(s2) * inv, COS_EPS);
            float cn = fmaxf(sqrtf(c2), COS_EPS);
            float censim = (pc * inv) / (pn * cn);
            float vw = 1.0f / (1.0f + sv * (1.0f / 128.0f));
            float a = censim * vw * STAT_ADJ_W;
            float pt = PN[c] + PN[2 * (size_t)C + c];          // A + B
            float nt = PN[(size_t)C + c] + PN[3 * (size_t)C + c];
            lp = log1pf(pt * __expf(-ALPHA * a));
            ln = log1pf(nt * __expf( ALPHA * a));
            nv = 1.f;
        }
    }

    // unowned classes: grid-stride; p == 0 exactly -> term is log1p(n)
    for (int cl = b * 256 + tid; cl < C; cl += nblk * 256) {
        float pt = PN[cl] + PN[2 * (size_t)C + cl];
        if (!(pt > 0.f))
            ln += log1pf(PN[(size_t)C + cl] + PN[3 * (size_t)C + cl]);
    }

    // block totals -> scal atomics; finisher = proven k_fin pattern
    #pragma unroll
    for (int off = 1; off < 64; off <<= 1) {
        lp += __shfl_xor(lp, off);
        ln += __shfl_xor(ln, off);
        nv += __shfl_xor(nv, off);
    }
    if (lane == 0) { red[wv][0] = lp; red[wv][1] = ln; red[wv][2] = nv; }
    __syncthreads();
    if (tid == 0) {
        atomicAdd(&scal[0], red[0][0] + red[1][0] + red[2][0] + red[3][0]);
        atomicAdd(&scal[1], red[0][1] + red[1][1] + red[2][1] + red[3][1]);
        atomicAdd(&scal[3], red[0][2] + red[1][2] + red[2][2] + red[3][2]);
        __threadfence();
        unsigned old = atomicAdd((unsigned*)(scal + 4), 1u);
        if (old == (unsigned)(nblk - 1)) {       // last finisher assembles out
            float S0 = atomicAdd(&scal[0], 0.f);
            float S1 = atomicAdd(&scal[1], 0.f);
            float S2 = atomicAdd(&scal[2], 0.f);
            float S3 = atomicAdd(&scal[3], 0.f);
            out[0] = S0 / S3 + S1 / (float)C + STAT_WEIGHT * (S2 / ((float)C * 128.f));
        }
    }
}

extern "C" void kernel_launch(void* const* d_in, const int* in_sizes, int n_in,
                              void* d_out, int out_size, void* d_ws, size_t ws_size,
                              hipStream_t stream) {
    const float* X       = (const float*)d_in[0];
    const int*   T       = (const int*)d_in[1];
    const float* proxies = (const float*)d_in[2];
    const float* cc      = (const float*)d_in[3];
    float* out = (float*)d_out;

    const int B = in_sizes[1];            // 512
    const int D = in_sizes[0] / B;        // 128
    const int C = in_sizes[2] / D;        // 50000

    // workspace: [PA C][NA C][PB C][NB C][scal 8]
    float* PN   = (float*)d_ws;
    float* scal = PN + 4 * (size_t)C;                  // 8

    const int nslice = (C + 127) / 128;                // 391

    k_main<<<512, 256, 0, stream>>>(X, proxies, T, PN, scal, C, nslice);
    k_sf<<<B, 256, 0, stream>>>(X, proxies, cc, T, PN, scal, out, C, B, B);
}

// Round 14
// 128.465 us; speedup vs baseline: 1.2094x; 1.2094x over previous
//
#include <hip/hip_runtime.h>
#include <math.h>

#define ALPHA 32.0f
#define MRG 0.1f
#define STAT_WEIGHT 0.01f
#define STAT_ADJ_W 0.15f
#define COS_EPS 1e-8f

typedef __attribute__((ext_vector_type(8))) short bf16x8;
typedef __attribute__((ext_vector_type(4))) float f32x4;
typedef __attribute__((ext_vector_type(4))) unsigned int u32x4;

__device__ __forceinline__ ushort f2bf(float f) {
    unsigned u = __float_as_uint(f);
    return (ushort)((u + 0x7FFFu + ((u >> 16) & 1u)) >> 16);   // RNE
}
__device__ __forceinline__ unsigned pk2(float a, float b) {
    return (unsigned)f2bf(a) | ((unsigned)f2bf(b) << 16);
}

// 128-active-lane block reduce (tid<128 contribute; all 256 threads barrier).
// Values bit-identical to the original 128-thread bred128.
__device__ __forceinline__ float bredL(float v, float* sm, int tid) {
    #pragma unroll
    for (int off = 1; off < 64; off <<= 1) v += __shfl_xor(v, off);
    if ((tid & 63) == 0 && tid < 128) sm[tid >> 6] = v;
    __syncthreads();
    float r = sm[0] + sm[1];
    __syncthreads();
    return r;
}

// ---------------- K1: 256-thread stats (proven R10) --------------------------
// Small LDS (~4.5 KB) -> high residency: cc scan at full TLP, owner-loop
// latency chains at 2x waves/CU. Writes coalesced swizzled Xn16 (R13 lesson:
// coalesced staging beats per-thread-row recompute). scal zero folded in.
__global__ void k_stats(const float* __restrict__ X, const float* __restrict__ proxies,
                        const float* __restrict__ cc, const int* __restrict__ T,
                        ushort* __restrict__ Xn16, float* __restrict__ adj,
                        float* __restrict__ scal, float* __restrict__ cabs_part,
                        int C, int B) {
    const int tid = threadIdx.x, b = blockIdx.x;
    const int lane = tid & 63, wv = tid >> 6;
    const int d = tid & 127;
    const bool lo = tid < 128;
    __shared__ int Tl[512];
    __shared__ int mlist[512];
    __shared__ float sm[2];
    __shared__ float smc[4];
    __shared__ int mcnt;

    if (b == 0 && tid < 8) scal[tid] = 0.f;      // consumed by later dispatches

    Tl[tid] = T[tid]; Tl[tid + 256] = T[tid + 256];
    if (tid == 0) mcnt = 0;

    // cc |.| grid-strided partial (plain per-block store)
    float cabs = 0.f;
    {
        const float4* cp = (const float4*)cc;
        const int n4 = C * 32;
        #pragma unroll 4
        for (int i = b * 256 + tid; i < n4; i += B * 256) {
            float4 v = cp[i];
            cabs += fabsf(v.x) + fabsf(v.y) + fabsf(v.z) + fabsf(v.w);
        }
    }
    #pragma unroll
    for (int off = 1; off < 64; off <<= 1) cabs += __shfl_xor(cabs, off);
    if (lane == 0) smc[wv] = cabs;
    __syncthreads();                              // also covers Tl/mcnt init
    if (tid == 0) cabs_part[b] = (smc[0] + smc[1]) + (smc[2] + smc[3]);

    const int c = Tl[b];

    // own row: normalize + swizzled bf16 store (values identical: hi lanes add 0)
    {
        float x = lo ? X[(size_t)b * 128 + d] : 0.f;
        float n2 = bredL(x * x, sm, tid);
        float xn = x * rsqrtf(n2 + 1e-12f);
        if (lo) {
            const int pk = ((((d >> 3) ^ (b & 15)) << 3) | (d & 7));
            Xn16[(size_t)b * 128 + pk] = f2bf(xn);
        }
    }

    // parallel membership scan (mlist order irrelevant: min + rank-sort)
    for (int j = tid; j < B; j += 256)
        if (Tl[j] == c) mlist[atomicAdd(&mcnt, 1)] = j;
    __syncthreads();
    const int cnt = mcnt;
    int minj = mlist[0];
    for (int i = 1; i < cnt; ++i) minj = min(minj, mlist[i]);
    if (minj != b) return;                        // earlier block owns this class

    // member stats in ascending-j order (bit-identical to serial original)
    float sd = 0.f, qd = 0.f;
    int prev = -1;
    for (int rank = 0; rank < cnt; ++rank) {
        int cur = 0x7fffffff;
        for (int i = 0; i < cnt; ++i) { int v = mlist[i]; if (v > prev && v < cur) cur = v; }
        prev = cur;
        float xj = lo ? X[(size_t)cur * 128 + d] : 0.f;
        float nj = bredL(xj * xj, sm, tid);
        float xnj = xj * rsqrtf(nj + 1e-12f);
        sd += xnj; qd += xnj * xnj;
    }
    float fc = (float)cnt;
    float m = sd / fc;
    float var = fminf(fmaxf(qd / fc - m * m, 1e-6f), 10.0f);
    float sv = bredL(var, sm, tid);

    float p  = lo ? proxies[(size_t)c * 128 + d] : 0.f;
    float cv = lo ? cc[(size_t)c * 128 + d] : 0.f;
    float s2 = bredL(p * p, sm, tid);
    float c2 = bredL(cv * cv, sm, tid);
    float pc = bredL(p * cv, sm, tid);
    if (tid == 0) {
        float inv = rsqrtf(s2 + 1e-12f);
        float pn = fmaxf(sqrtf(s2) * inv, COS_EPS);
        float cn = fmaxf(sqrtf(c2), COS_EPS);
        float censim = (pc * inv) / (pn * cn);
        float vw = 1.0f / (1.0f + sv * (1.0f / 128.0f));
        adj[c] = censim * vw * STAT_ADJ_W;
    }
}

// ---------------- K2: persistent blocks, rows staged ONCE, barrier-free loop --
// Proven R10 body: (256,2) grid, 64 KB LDS, coalesced contiguous staging of
// the swizzled Xn16 half, barrier-free slice loop with desymmetrized start,
// single-writer plain stores into PA/PB (quarters A/B -> deterministic).
__launch_bounds__(256, 2)
__global__ void k_main(const float* __restrict__ proxies, const ushort* __restrict__ Xsw,
                       const int* __restrict__ T, float* __restrict__ PN,
                       int C, int nslice) {
    const int tid = threadIdx.x, lane = tid & 63, wv = tid >> 6;
    const int nlo = lane & 15, quad = lane >> 4;
    const int half = blockIdx.y;                  // 0/1: which 256-row half

    __shared__ ushort Sx[32768];                  // 64 KB: 256 rows x 128 bf16
    __shared__ alignas(16) int Tl[256];

    // ---- stage all 256 rows once (layout-preserving contiguous copy) ----
    {
        const uint4* src = (const uint4*)Xsw + half * 4096;
        uint4* dst = (uint4*)Sx;
        #pragma unroll
        for (int k = 0; k < 16; ++k) dst[tid + k * 256] = src[tid + k * 256];
    }
    Tl[tid] = T[half * 256 + tid];
    __syncthreads();                              // the ONLY barrier

    float* PA = PN + (size_t)half * 2 * C;        // half0 -> A, half1 -> B
    float* NA = PA + C;

    // ---- fragment LDS offsets (in ushorts); swizzle index is nlo ----
    int fro[4];
    #pragma unroll
    for (int ks = 0; ks < 4; ++ks)
        fro[ks] = nlo * 128 + (((ks * 4 + quad) ^ nlo) << 3);

    const int s0 = (blockIdx.x + (half ? 128 : 0)) & 255;   // desymmetrized start
    for (int s = s0; s < nslice; s += 256) {
        const int c0 = s * 128;
        const int cls0 = c0 + wv * 32 + nlo;
        const int cls1 = cls0 + 16;

        // B fragments: 2 class-tiles, normalized in-register (proven shape)
        bf16x8 bfr[2][4];
        #pragma unroll
        for (int t = 0; t < 2; ++t) {
            int cls = c0 + wv * 32 + t * 16 + nlo;
            int cl = (cls < C) ? cls : C - 1;
            const float4* pr = (const float4*)(proxies + (size_t)cl * 128);
            float4 v0[4], v1[4];
            float s2 = 0.f;
            #pragma unroll
            for (int ks = 0; ks < 4; ++ks) {
                v0[ks] = pr[ks * 8 + quad * 2];
                v1[ks] = pr[ks * 8 + quad * 2 + 1];
                s2 += v0[ks].x*v0[ks].x + v0[ks].y*v0[ks].y + v0[ks].z*v0[ks].z + v0[ks].w*v0[ks].w
                    + v1[ks].x*v1[ks].x + v1[ks].y*v1[ks].y + v1[ks].z*v1[ks].z + v1[ks].w*v1[ks].w;
            }
            s2 += __shfl_xor(s2, 16);
            s2 += __shfl_xor(s2, 32);
            float pin = rsqrtf(s2 + 1e-12f);
            #pragma unroll
            for (int ks = 0; ks < 4; ++ks) {
                u32x4 u;
                u.x = pk2(v0[ks].x * pin, v0[ks].y * pin);
                u.y = pk2(v0[ks].z * pin, v0[ks].w * pin);
                u.z = pk2(v1[ks].x * pin, v1[ks].y * pin);
                u.w = pk2(v1[ks].z * pin, v1[ks].w * pin);
                bfr[t][ks] = __builtin_bit_cast(bf16x8, u);
            }
        }

        float pp0 = 0.f, np0 = 0.f, pp1 = 0.f, np1 = 0.f;
        #pragma unroll 4
        for (int rt = 0; rt < 16; ++rt) {
            const ushort* sb = &Sx[rt * 2048];
            bf16x8 a0 = *(const bf16x8*)&sb[fro[0]];
            bf16x8 a1 = *(const bf16x8*)&sb[fro[1]];
            bf16x8 a2 = *(const bf16x8*)&sb[fro[2]];
            bf16x8 a3 = *(const bf16x8*)&sb[fro[3]];
            f32x4 acc0 = {0.f,0.f,0.f,0.f}, acc1 = {0.f,0.f,0.f,0.f};
            acc0 = __builtin_amdgcn_mfma_f32_16x16x32_bf16(a0, bfr[0][0], acc0, 0, 0, 0);
            acc1 = __builtin_amdgcn_mfma_f32_16x16x32_bf16(a0, bfr[1][0], acc1, 0, 0, 0);
            acc0 = __builtin_amdgcn_mfma_f32_16x16x32_bf16(a1, bfr[0][1], acc0, 0, 0, 0);
            acc1 = __builtin_amdgcn_mfma_f32_16x16x32_bf16(a1, bfr[1][1], acc1, 0, 0, 0);
            acc0 = __builtin_amdgcn_mfma_f32_16x16x32_bf16(a2, bfr[0][2], acc0, 0, 0, 0);
            acc1 = __builtin_amdgcn_mfma_f32_16x16x32_bf16(a2, bfr[1][2], acc1, 0, 0, 0);
            acc0 = __builtin_amdgcn_mfma_f32_16x16x32_bf16(a3, bfr[0][3], acc0, 0, 0, 0);
            acc1 = __builtin_amdgcn_mfma_f32_16x16x32_bf16(a3, bfr[1][3], acc1, 0, 0, 0);

            int4 t4 = *(const int4*)&Tl[rt * 16 + quad * 4];
            int tvs[4] = {t4.x, t4.y, t4.z, t4.w};
            #pragma unroll
            for (int r = 0; r < 4; ++r) {
                { bool po = (tvs[r] == cls0); float v = acc0[r];
                  float e = __expf(po ? -ALPHA * (v - MRG) : ALPHA * (v + MRG));
                  pp0 += po ? e : 0.f; np0 += po ? 0.f : e; }
                { bool po = (tvs[r] == cls1); float v = acc1[r];
                  float e = __expf(po ? -ALPHA * (v - MRG) : ALPHA * (v + MRG));
                  pp1 += po ? e : 0.f; np1 += po ? 0.f : e; }
            }
        }

        // per-class half-totals across quads -> PLAIN stores (single writer)
        pp0 += __shfl_xor(pp0, 16); pp0 += __shfl_xor(pp0, 32);
        np0 += __shfl_xor(np0, 16); np0 += __shfl_xor(np0, 32);
        pp1 += __shfl_xor(pp1, 16); pp1 += __shfl_xor(pp1, 32);
        np1 += __shfl_xor(np1, 16); np1 += __shfl_xor(np1, 32);
        if (quad == 0) {
            if (cls0 < C) { PA[cls0] = pp0; NA[cls0] = np0; }
            if (cls1 < C) { PA[cls1] = pp1; NA[cls1] = np1; }
        }
    }
}

// ---------------- K3: combine A+B, per-class log1p, final reduce -------------
__launch_bounds__(256)
__global__ void k_fin(const float* __restrict__ PN, const float* __restrict__ adj,
                      const float* __restrict__ cabs_part, float* __restrict__ scal,
                      float* __restrict__ out, int C, int nfin) {
    const int tid = threadIdx.x, lane = tid & 63, wv = tid >> 6;
    const int c = blockIdx.x * 256 + tid;
    __shared__ float red[4][3];
    float lp = 0.f, ln = 0.f, nv = 0.f;
    if (c < C) {
        float p = PN[c] + PN[2 * (size_t)C + c];           // A + B (fixed order)
        float n = PN[(size_t)C + c] + PN[3 * (size_t)C + c];
        float a = 0.f;
        if (p > 0.f) { a = adj[c]; nv = 1.f; }             // has_samples <=> p>0
        lp = log1pf(p * __expf(-ALPHA * a));
        ln = log1pf(n * __expf( ALPHA * a));
    }
    #pragma unroll
    for (int off = 1; off < 64; off <<= 1) {
        lp += __shfl_xor(lp, off);
        ln += __shfl_xor(ln, off);
        nv += __shfl_xor(nv, off);
    }
    if (lane == 0) { red[wv][0] = lp; red[wv][1] = ln; red[wv][2] = nv; }
    __syncthreads();
    if (tid == 0) {
        atomicAdd(&scal[0], red[0][0] + red[1][0] + red[2][0] + red[3][0]);
        atomicAdd(&scal[1], red[0][1] + red[1][1] + red[2][1] + red[3][1]);
        atomicAdd(&scal[3], red[0][2] + red[1][2] + red[2][2] + red[3][2]);
    }
    // block 0: cabs_part[512] sum -> scal[2]
    if (blockIdx.x == 0) {
        float cb = cabs_part[tid] + cabs_part[tid + 256];
        #pragma unroll
        for (int off = 1; off < 64; off <<= 1) cb += __shfl_xor(cb, off);
        __syncthreads();
        if (lane == 0) red[wv][0] = cb;
        __syncthreads();
        if (tid == 0) atomicAdd(&scal[2], red[0][0] + red[1][0] + red[2][0] + red[3][0]);
    }
    if (tid == 0) {
        __threadfence();
        unsigned old = atomicAdd((unsigned*)(scal + 4), 1u);
        if (old == (unsigned)(nfin - 1)) {       // last finisher assembles out
            float S0 = atomicAdd(&scal[0], 0.f);
            float S1 = atomicAdd(&scal[1], 0.f);
            float S2 = atomicAdd(&scal[2], 0.f);
            float S3 = atomicAdd(&scal[3], 0.f);
            out[0] = S0 / S3 + S1 / (float)C + STAT_WEIGHT * (S2 / ((float)C * 128.f));
        }
    }
}

extern "C" void kernel_launch(void* const* d_in, const int* in_sizes, int n_in,
                              void* d_out, int out_size, void* d_ws, size_t ws_size,
                              hipStream_t stream) {
    const float* X       = (const float*)d_in[0];
    const int*   T       = (const int*)d_in[1];
    const float* proxies = (const float*)d_in[2];
    const float* cc      = (const float*)d_in[3];
    float* out = (float*)d_out;

    const int B = in_sizes[1];            // 512
    const int D = in_sizes[0] / B;        // 128
    const int C = in_sizes[2] / D;        // 50000

    // workspace: [PA C][NA C][PB C][NB C][scal 8][cabs_part 512][adj C][Xn16]
    float*  PN   = (float*)d_ws;
    float*  scal = PN + 4 * (size_t)C;                 // 8
    float*  cabs_part = scal + 8;                      // 512
    float*  adj  = cabs_part + 512;                    // C
    ushort* Xn16 = (ushort*)(adj + C);                 // B*D bf16, swizzled

    const int nslice = (C + 127) / 128;                // 391
    const int nfin   = (C + 255) / 256;                // 196

    k_stats<<<B, 256, 0, stream>>>(X, proxies, cc, T, Xn16, adj, scal,
                                   cabs_part, C, B);
    k_main<<<dim3(256, 2), 256, 0, stream>>>(proxies, Xn16, T, PN, C, nslice);
    k_fin<<<nfin, 256, 0, stream>>>(PN, adj, cabs_part, scal, out, C, nfin);
}